// Round 3
// baseline (1428331.738 us; speedup 1.0000x reference)
//
#include <hip/hip_runtime.h>
#include <math.h>

#define TT 1024
#define BB 128
#define HH 256

__device__ __forceinline__ float sigm(float x) { return 1.0f / (1.0f + expf(-x)); }

// One persistent WG per (group, hidden-slice). Group = 16 WGs covering all 256
// hidden units for C16 = CHUNKS*16 chains. Weights live in LDS for the whole
// layer; h is exchanged between the 16 WGs of a group via double-buffered
// global hbuf + per-group arrival counter.
// Liveness: the barrier POLLS WITH AN ATOMIC RMW (fetch_add 0, agent scope).
// A plain atomic load can be satisfied by a stale line in the polling XCD's
// L2 (SDMA memsets / other XCDs' RMWs don't invalidate it) and then only
// resolves on random eviction -- that was round 1's 1.1s/replay failure mode.
// RMWs execute at the memory-side atomic unit (same path as the writer's
// fetch_add), so every poll is fresh.
template <int CHUNKS, int NSLX>
__global__ __launch_bounds__(256, 1) void lstm_layer(
    const float* __restrict__ X, float* __restrict__ Y,
    const float* __restrict__ Wih, const float* __restrict__ Whh,
    const float* __restrict__ bih, const float* __restrict__ bhh,
    float* __restrict__ hbuf, unsigned int* __restrict__ ctr,
    int n_steps, int rate, size_t HB) {
  constexpr int Din = NSLX * 128;
  constexpr int Dtot = Din + HH;
  constexpr int C16 = CHUNKS * 16;

  extern __shared__ float lds[];
  float* Wl = lds;             // [Dtot][64]  (d slow; 64 = 16 units x 4 gates fast)
  float* xh = lds + Dtot * 64; // [C16][132]  staging, padded pitch

  const int tid = threadIdx.x;
  const int jj = tid & 15;   // hidden unit within slice
  const int ccl = tid >> 4;  // chain within 16-chunk
  const int group = blockIdx.x >> 4;
  const int slice = blockIdx.x & 15;
  const int unit = slice * 16 + jj;

  // One-time: load this WG's 64 fused weight rows into LDS, transposed to [d][rr].
  for (int idx = tid; idx < Dtot * 64; idx += 256) {
    int d = idx >> 6, rr = idx & 63;
    int grow = ((rr & 3) << 8) + slice * 16 + (rr >> 2); // gate*256 + unit
    Wl[idx] = (d < Din) ? Wih[(size_t)grow * Din + d]
                        : Whh[(size_t)grow * HH + (d - Din)];
  }
  float bsum[4];
#pragma unroll
  for (int g = 0; g < 4; ++g)
    bsum[g] = bih[(g << 8) + unit] + bhh[(g << 8) + unit];

  float creg[CHUNKS];
#pragma unroll
  for (int ch = 0; ch < CHUNKS; ++ch) creg[ch] = 0.f;

  __syncthreads();

  const int q00 = group * C16; // first global chain of this group
  const int toff = q00 >> 7;   // time offset (uniform per group; 16/32-aligned
                               // chain blocks never cross a 128 boundary)
  const int scc = tid >> 4;         // staging row within 16
  const int sd = (tid & 15) << 3;   // staging column (8 floats)
  bool dead = false;

  float acc[CHUNKS][4];

  for (int s = 0; s < n_steps; ++s) {
    float* hwrite = hbuf + (size_t)(s & 1) * HB;
    const float* hread = hbuf + (size_t)((s & 1) ^ 1) * HB;
    const int t = s * rate + toff;

#pragma unroll
    for (int ch = 0; ch < CHUNKS; ++ch)
#pragma unroll
      for (int g = 0; g < 4; ++g) acc[ch][g] = 0.f;

    // GEMM over one staged 128-d slice; W reads shared across chunks.
    auto gemm_slice = [&](const float* Wbase) {
      const float4* W4 = ((const float4*)Wbase) + jj;
      const float4* xh4 = (const float4*)xh;
#pragma unroll
      for (int d4 = 0; d4 < 32; ++d4) {
        float4 w0 = W4[(d4 * 4 + 0) * 16];
        float4 w1 = W4[(d4 * 4 + 1) * 16];
        float4 w2 = W4[(d4 * 4 + 2) * 16];
        float4 w3 = W4[(d4 * 4 + 3) * 16];
#pragma unroll
        for (int ch = 0; ch < CHUNKS; ++ch) {
          float4 xv = xh4[(ch * 16 + ccl) * 33 + d4];
          acc[ch][0] += xv.x * w0.x + xv.y * w1.x + xv.z * w2.x + xv.w * w3.x;
          acc[ch][1] += xv.x * w0.y + xv.y * w1.y + xv.z * w2.y + xv.w * w3.y;
          acc[ch][2] += xv.x * w0.z + xv.y * w1.z + xv.z * w2.z + xv.w * w3.z;
          acc[ch][3] += xv.x * w0.w + xv.y * w1.w + xv.z * w2.w + xv.w * w3.w;
        }
      }
    };

    // ---- x contribution: no cross-WG dependency, overlaps barrier wait ----
#pragma unroll
    for (int dsl = 0; dsl < NSLX; ++dsl) {
      __syncthreads();
#pragma unroll
      for (int ch = 0; ch < CHUNKS; ++ch) {
        const int q = q00 + (ch << 4) + scc;
        const float* src = X + ((size_t)t * BB + (q & 127)) * Din + (dsl << 7) + sd;
        *(float4*)&xh[(ch * 16 + scc) * 132 + sd] = *(const float4*)src;
        *(float4*)&xh[(ch * 16 + scc) * 132 + sd + 4] = *(const float4*)(src + 4);
      }
      __syncthreads();
      gemm_slice(Wl + (size_t)(dsl << 7) * 64);
    }

    // ---- wait until all 16 WGs of the group published h(s-1) ----
    if (s > 0) {
      if (tid == 0 && !dead) {
        const unsigned int target = 16u * (unsigned int)s;
        int spins = 0;
        for (;;) {
          // RMW poll: always served fresh by the memory-side atomic unit.
          unsigned int v = __hip_atomic_fetch_add(ctr + group, 0u,
                                                  __ATOMIC_ACQ_REL,
                                                  __HIP_MEMORY_SCOPE_AGENT);
          if (v >= target) break;
          __builtin_amdgcn_s_sleep(8);
          if (++spins > (1 << 20)) { dead = true; break; } // never hang the bench
        }
        __threadfence();
      }
      __syncthreads();
    }

    // ---- h contribution ----
#pragma unroll
    for (int dsl = 0; dsl < 2; ++dsl) {
      __syncthreads();
#pragma unroll
      for (int ch = 0; ch < CHUNKS; ++ch) {
        const int q = q00 + (ch << 4) + scc;
        const float* src = hread + (size_t)q * HH + (dsl << 7) + sd;
        *(float4*)&xh[(ch * 16 + scc) * 132 + sd] = *(const float4*)src;
        *(float4*)&xh[(ch * 16 + scc) * 132 + sd + 4] = *(const float4*)(src + 4);
      }
      __syncthreads();
      gemm_slice(Wl + (size_t)(Din + (dsl << 7)) * 64);
    }

    // ---- LSTM pointwise + writes ----
#pragma unroll
    for (int ch = 0; ch < CHUNKS; ++ch) {
      const int q = q00 + (ch << 4) + ccl;
      const int b = q & 127;
      float gi = sigm(acc[ch][0] + bsum[0]);
      float gf = sigm(acc[ch][1] + bsum[1]);
      float gg = tanhf(acc[ch][2] + bsum[2]);
      float go = sigm(acc[ch][3] + bsum[3]);
      float c = gf * creg[ch] + gi * gg;
      creg[ch] = c;
      float h = go * tanhf(c);
      hwrite[(size_t)q * HH + unit] = h;
      Y[((size_t)t * BB + b) * HH + unit] = h;
    }

    // ---- publish h(s) ----
    __threadfence();
    __syncthreads();
    if (tid == 0)
      __hip_atomic_fetch_add(ctr + group, 1u, __ATOMIC_RELEASE,
                             __HIP_MEMORY_SCOPE_AGENT);
  }
}

template <int C, int N>
static void launch_layer(dim3 grid, size_t lds, hipStream_t stream,
                         const float* X, float* Y, const float* Wih,
                         const float* Whh, const float* bih, const float* bhh,
                         float* hbuf, unsigned int* ctr, int n_steps, int rate,
                         size_t HB) {
  hipFuncSetAttribute(reinterpret_cast<const void*>(&lstm_layer<C, N>),
                      hipFuncAttributeMaxDynamicSharedMemorySize, (int)lds);
  lstm_layer<C, N><<<grid, dim3(256), lds, stream>>>(
      X, Y, Wih, Whh, bih, bhh, hbuf, ctr, n_steps, rate, HB);
}

extern "C" void kernel_launch(void* const* d_in, const int* in_sizes, int n_in,
                              void* d_out, int out_size, void* d_ws, size_t ws_size,
                              hipStream_t stream) {
  const float* x = (const float*)d_in[0];
  const float* Wih0 = (const float*)d_in[1];
  const float* Whh0 = (const float*)d_in[2];
  const float* bih0 = (const float*)d_in[3];
  const float* bhh0 = (const float*)d_in[4];
  const float* Wih1 = (const float*)d_in[5];
  const float* Whh1 = (const float*)d_in[6];
  const float* bih1 = (const float*)d_in[7];
  const float* bhh1 = (const float*)d_in[8];
  const float* Wih2 = (const float*)d_in[9];
  const float* Whh2 = (const float*)d_in[10];
  const float* bih2 = (const float*)d_in[11];
  const float* bhh2 = (const float*)d_in[12];

  const size_t outElems = (size_t)TT * BB * HH; // 33,554,432
  float* out0 = (float*)d_ws;                   // 134 MB scratch output
  float* hbuf = (float*)((char*)d_ws + outElems * sizeof(float)); // 1 MB
  unsigned int* ctr =
      (unsigned int*)((char*)hbuf + (size_t)2 * 512 * HH * sizeof(float));
  float* dout = (float*)d_out;

  const size_t hcBytes = (size_t)2 * 512 * HH * sizeof(float) + 256; // hbuf+ctr

  // LDS: Wl = Dtot*64 floats, xh = CHUNKS*16*132 floats
  const size_t lds0 = (384 * 64 + 16 * 132) * sizeof(float);  // 106,752
  const size_t lds12 = (512 * 64 + 32 * 132) * sizeof(float); // 147,968

  // Layer 0: rate 1, Beff 128, Din 128 -> 8 groups x 16 WGs = 128 (slack)
  hipMemsetAsync(hbuf, 0, hcBytes, stream);
  launch_layer<1, 1>(dim3(128), lds0, stream, x, out0, Wih0, Whh0, bih0, bhh0,
                     hbuf, ctr, 1024, 1, (size_t)128 * HH);

  // Layer 1: rate 2, Beff 256, Din 256 -> 8 groups x 16 WGs = 128, CHUNKS=2 (slack)
  hipMemsetAsync(hbuf, 0, hcBytes, stream);
  launch_layer<2, 2>(dim3(128), lds12, stream, out0, dout, Wih1, Whh1, bih1,
                     bhh1, hbuf, ctr, 512, 2, (size_t)256 * HH);

  // Layer 2: rate 4, Beff 512, Din 256 -> 16 groups x 16 WGs = 256, CHUNKS=2
  hipMemsetAsync(hbuf, 0, hcBytes, stream);
  launch_layer<2, 2>(dim3(256), lds12, stream, dout, out0, Wih2, Whh2, bih2,
                     bhh2, hbuf, ctr, 256, 4, (size_t)512 * HH);

  // final result back to d_out
  hipMemcpyAsync(d_out, out0, outElems * sizeof(float), hipMemcpyDeviceToDevice,
                 stream);
}

// Round 4
// 1262397.656 us; speedup vs baseline: 1.1314x; 1.1314x over previous
//
#include <hip/hip_runtime.h>
#include <math.h>

#define TT 1024
#define BB 128
#define HH 256

__device__ __forceinline__ float sigm(float x) { return 1.0f / (1.0f + expf(-x)); }

// One persistent WG per (group, hidden-slice). Group = 16 WGs covering all 256
// hidden units for C16 = CHUNKS*16 chains. Weights live in LDS for the whole
// layer; h is exchanged between the 16 WGs of a group via double-buffered
// global hbuf + per-group arrival counter (one counter per 128B line).
//
// Barrier protocol (the hard-won part):
//  - POLL with RELAXED atomic RMW (fetch_add 0, agent scope). RMWs always
//    execute at the memory-side atomic unit -> always fresh, and relaxed
//    order emits NO per-poll L2 writeback/invalidate. (ACQ_REL polling =
//    full buffer_wbl2+buffer_inv per iteration = the 1.4s L2-flush storm of
//    round 3; ACQUIRE-load polling = buffer_inv storm + stale-eviction waits
//    = round 1's dead-latch corruption.)
//  - Ordering established ONCE per barrier: writer's RELEASE fetch_add does
//    one wbl2 (flushes its XCD's dirty h/Y lines); readers do one agent
//    ACQUIRE fence in ALL waves (one buffer_inv each, also covers L1).
template <int CHUNKS, int NSLX>
__global__ __launch_bounds__(256, 1) void lstm_layer(
    const float* __restrict__ X, float* __restrict__ Y,
    const float* __restrict__ Wih, const float* __restrict__ Whh,
    const float* __restrict__ bih, const float* __restrict__ bhh,
    float* __restrict__ hbuf, unsigned int* __restrict__ ctr,
    int n_steps, int rate, size_t HB) {
  constexpr int Din = NSLX * 128;
  constexpr int Dtot = Din + HH;
  constexpr int C16 = CHUNKS * 16;

  extern __shared__ float lds[];
  float* Wl = lds;             // [Dtot][64]  (d slow; 64 = 16 units x 4 gates fast)
  float* xh = lds + Dtot * 64; // [C16][132]  staging, padded pitch

  const int tid = threadIdx.x;
  const int jj = tid & 15;   // hidden unit within slice
  const int ccl = tid >> 4;  // chain within 16-chunk
  const int group = blockIdx.x >> 4;
  const int slice = blockIdx.x & 15;
  const int unit = slice * 16 + jj;
  unsigned int* const myctr = ctr + (group << 5); // 128B-padded counter

  // One-time: load this WG's 64 fused weight rows into LDS, transposed to [d][rr].
  for (int idx = tid; idx < Dtot * 64; idx += 256) {
    int d = idx >> 6, rr = idx & 63;
    int grow = ((rr & 3) << 8) + slice * 16 + (rr >> 2); // gate*256 + unit
    Wl[idx] = (d < Din) ? Wih[(size_t)grow * Din + d]
                        : Whh[(size_t)grow * HH + (d - Din)];
  }
  float bsum[4];
#pragma unroll
  for (int g = 0; g < 4; ++g)
    bsum[g] = bih[(g << 8) + unit] + bhh[(g << 8) + unit];

  float creg[CHUNKS];
#pragma unroll
  for (int ch = 0; ch < CHUNKS; ++ch) creg[ch] = 0.f;

  __syncthreads();

  const int q00 = group * C16; // first global chain of this group
  const int toff = q00 >> 7;   // time offset (uniform per group; 16/32-aligned
                               // chain blocks never cross a 128 boundary)
  const int scc = tid >> 4;         // staging row within 16
  const int sd = (tid & 15) << 3;   // staging column (8 floats)
  bool dead = false;

  float acc[CHUNKS][4];

  for (int s = 0; s < n_steps; ++s) {
    float* hwrite = hbuf + (size_t)(s & 1) * HB;
    const float* hread = hbuf + (size_t)((s & 1) ^ 1) * HB;
    const int t = s * rate + toff;

#pragma unroll
    for (int ch = 0; ch < CHUNKS; ++ch)
#pragma unroll
      for (int g = 0; g < 4; ++g) acc[ch][g] = 0.f;

    // GEMM over one staged 128-d slice; W reads shared across chunks.
    auto gemm_slice = [&](const float* Wbase) {
      const float4* W4 = ((const float4*)Wbase) + jj;
      const float4* xh4 = (const float4*)xh;
#pragma unroll
      for (int d4 = 0; d4 < 32; ++d4) {
        float4 w0 = W4[(d4 * 4 + 0) * 16];
        float4 w1 = W4[(d4 * 4 + 1) * 16];
        float4 w2 = W4[(d4 * 4 + 2) * 16];
        float4 w3 = W4[(d4 * 4 + 3) * 16];
#pragma unroll
        for (int ch = 0; ch < CHUNKS; ++ch) {
          float4 xv = xh4[(ch * 16 + ccl) * 33 + d4];
          acc[ch][0] += xv.x * w0.x + xv.y * w1.x + xv.z * w2.x + xv.w * w3.x;
          acc[ch][1] += xv.x * w0.y + xv.y * w1.y + xv.z * w2.y + xv.w * w3.y;
          acc[ch][2] += xv.x * w0.z + xv.y * w1.z + xv.z * w2.z + xv.w * w3.z;
          acc[ch][3] += xv.x * w0.w + xv.y * w1.w + xv.z * w2.w + xv.w * w3.w;
        }
      }
    };

    // ---- x contribution: no cross-WG dependency, overlaps barrier wait ----
#pragma unroll
    for (int dsl = 0; dsl < NSLX; ++dsl) {
      __syncthreads();
#pragma unroll
      for (int ch = 0; ch < CHUNKS; ++ch) {
        const int q = q00 + (ch << 4) + scc;
        const float* src = X + ((size_t)t * BB + (q & 127)) * Din + (dsl << 7) + sd;
        *(float4*)&xh[(ch * 16 + scc) * 132 + sd] = *(const float4*)src;
        *(float4*)&xh[(ch * 16 + scc) * 132 + sd + 4] = *(const float4*)(src + 4);
      }
      __syncthreads();
      gemm_slice(Wl + (size_t)(dsl << 7) * 64);
    }

    // ---- wait until all 16 WGs of the group published h(s-1) ----
    if (s > 0) {
      if (tid == 0 && !dead) {
        const unsigned int target = 16u * (unsigned int)s;
        int spins = 0;
        for (;;) {
          // RELAXED RMW poll: memory-side (always fresh), no fence traffic.
          unsigned int v = __hip_atomic_fetch_add(myctr, 0u, __ATOMIC_RELAXED,
                                                  __HIP_MEMORY_SCOPE_AGENT);
          if (v >= target) break;
          __builtin_amdgcn_s_sleep(2);
          if (++spins > (1 << 20)) { dead = true; break; } // never hang the bench
        }
      }
      __syncthreads();
      // One acquire per barrier, ALL waves: invalidates stale L1/L2 copies of
      // hread before anyone loads it.
      __builtin_amdgcn_fence(__ATOMIC_ACQUIRE, "agent");
    }

    // ---- h contribution ----
#pragma unroll
    for (int dsl = 0; dsl < 2; ++dsl) {
      __syncthreads();
#pragma unroll
      for (int ch = 0; ch < CHUNKS; ++ch) {
        const int q = q00 + (ch << 4) + scc;
        const float* src = hread + (size_t)q * HH + (dsl << 7) + sd;
        *(float4*)&xh[(ch * 16 + scc) * 132 + sd] = *(const float4*)src;
        *(float4*)&xh[(ch * 16 + scc) * 132 + sd + 4] = *(const float4*)(src + 4);
      }
      __syncthreads();
      gemm_slice(Wl + (size_t)(Din + (dsl << 7)) * 64);
    }

    // ---- LSTM pointwise + writes ----
#pragma unroll
    for (int ch = 0; ch < CHUNKS; ++ch) {
      const int q = q00 + (ch << 4) + ccl;
      const int b = q & 127;
      float gi = sigm(acc[ch][0] + bsum[0]);
      float gf = sigm(acc[ch][1] + bsum[1]);
      float gg = tanhf(acc[ch][2] + bsum[2]);
      float go = sigm(acc[ch][3] + bsum[3]);
      float c = gf * creg[ch] + gi * gg;
      creg[ch] = c;
      float h = go * tanhf(c);
      hwrite[(size_t)q * HH + unit] = h;
      Y[((size_t)t * BB + b) * HH + unit] = h;
    }

    // ---- publish h(s): syncthreads drains vmcnt; RELEASE RMW does one wbl2
    //      (flushes this XCD's dirty h/Y lines) then bumps the counter.
    __syncthreads();
    if (tid == 0)
      __hip_atomic_fetch_add(myctr, 1u, __ATOMIC_RELEASE,
                             __HIP_MEMORY_SCOPE_AGENT);
  }
}

template <int C, int N>
static void launch_layer(dim3 grid, size_t lds, hipStream_t stream,
                         const float* X, float* Y, const float* Wih,
                         const float* Whh, const float* bih, const float* bhh,
                         float* hbuf, unsigned int* ctr, int n_steps, int rate,
                         size_t HB) {
  hipFuncSetAttribute(reinterpret_cast<const void*>(&lstm_layer<C, N>),
                      hipFuncAttributeMaxDynamicSharedMemorySize, (int)lds);
  lstm_layer<C, N><<<grid, dim3(256), lds, stream>>>(
      X, Y, Wih, Whh, bih, bhh, hbuf, ctr, n_steps, rate, HB);
}

extern "C" void kernel_launch(void* const* d_in, const int* in_sizes, int n_in,
                              void* d_out, int out_size, void* d_ws, size_t ws_size,
                              hipStream_t stream) {
  const float* x = (const float*)d_in[0];
  const float* Wih0 = (const float*)d_in[1];
  const float* Whh0 = (const float*)d_in[2];
  const float* bih0 = (const float*)d_in[3];
  const float* bhh0 = (const float*)d_in[4];
  const float* Wih1 = (const float*)d_in[5];
  const float* Whh1 = (const float*)d_in[6];
  const float* bih1 = (const float*)d_in[7];
  const float* bhh1 = (const float*)d_in[8];
  const float* Wih2 = (const float*)d_in[9];
  const float* Whh2 = (const float*)d_in[10];
  const float* bih2 = (const float*)d_in[11];
  const float* bhh2 = (const float*)d_in[12];

  const size_t outElems = (size_t)TT * BB * HH; // 33,554,432
  float* out0 = (float*)d_ws;                   // 134 MB scratch output
  float* hbuf = (float*)((char*)d_ws + outElems * sizeof(float)); // 1 MB
  unsigned int* ctr =
      (unsigned int*)((char*)hbuf + (size_t)2 * 512 * HH * sizeof(float));
  float* dout = (float*)d_out;

  // hbuf + 16 groups x 32-uint (128B) padded counters
  const size_t hcBytes = (size_t)2 * 512 * HH * sizeof(float) + 16 * 128;

  // LDS: Wl = Dtot*64 floats, xh = CHUNKS*16*132 floats
  const size_t lds0 = (384 * 64 + 16 * 132) * sizeof(float);  // 106,752
  const size_t lds12 = (512 * 64 + 32 * 132) * sizeof(float); // 147,968

  // Layer 0: rate 1, Beff 128, Din 128 -> 8 groups x 16 WGs = 128
  hipMemsetAsync(hbuf, 0, hcBytes, stream);
  launch_layer<1, 1>(dim3(128), lds0, stream, x, out0, Wih0, Whh0, bih0, bhh0,
                     hbuf, ctr, 1024, 1, (size_t)128 * HH);

  // Layer 1: rate 2, Beff 256, Din 256 -> 8 groups x 16 WGs = 128, CHUNKS=2
  hipMemsetAsync(hbuf, 0, hcBytes, stream);
  launch_layer<2, 2>(dim3(128), lds12, stream, out0, dout, Wih1, Whh1, bih1,
                     bhh1, hbuf, ctr, 512, 2, (size_t)256 * HH);

  // Layer 2: rate 4, Beff 512, Din 256 -> 16 groups x 16 WGs = 256, CHUNKS=2
  hipMemsetAsync(hbuf, 0, hcBytes, stream);
  launch_layer<2, 2>(dim3(256), lds12, stream, dout, out0, Wih2, Whh2, bih2,
                     bhh2, hbuf, ctr, 256, 4, (size_t)512 * HH);

  // final result back to d_out
  hipMemcpyAsync(d_out, out0, outElems * sizeof(float), hipMemcpyDeviceToDevice,
                 stream);
}